// Round 21
// baseline (141.151 us; speedup 1.0000x reference)
//
#include <hip/hip_runtime.h>

using u16 = unsigned short;
using u32 = unsigned int;

#define B_   2
#define N_   2048
#define DIM_ 1024
#define H_   16
#define D_   64
#define ROWS_ (B_*N_)   // 4096
#define E3_  3072       // q|k|v concatenated

typedef __attribute__((ext_vector_type(8))) short short8;
typedef __attribute__((ext_vector_type(4))) short short4v;
typedef __attribute__((ext_vector_type(4))) float f32x4;

__device__ __forceinline__ u16 f2bf(float f) {
  u32 u = __builtin_bit_cast(u32, f);
  u32 r = (u + 0x7FFFu + ((u >> 16) & 1u)) >> 16;
  return (u16)r;
}
__device__ __forceinline__ float bf2f(u16 h) {
  u32 u = ((u32)h) << 16;
  return __builtin_bit_cast(float, u);
}
__device__ __forceinline__ short8 ld8(const u16* p) { return *(const short8*)p; }
__device__ __forceinline__ f32x4 mfma16(short8 a, short8 b, f32x4 c) {
  return __builtin_amdgcn_mfma_f32_16x16x32_bf16(a, b, c, 0, 0, 0);
}
// K=16 bf16 MFMA (R9-verified): B[k=g*4+j][col=li] == softmax's in-lane P.
__device__ __forceinline__ f32x4 mfma16k16(short4v a, short4v b, f32x4 c) {
#if !defined(__HIP_DEVICE_COMPILE__)
  (void)a; (void)b;
  return c;
#elif __has_builtin(__builtin_amdgcn_mfma_f32_16x16x16bf16_1k)
  return __builtin_amdgcn_mfma_f32_16x16x16bf16_1k(a, b, c, 0, 0, 0);
#else
  short8 a8 = (short8){a[0], a[1], a[2], a[3], 0, 0, 0, 0};
  short8 b8 = (short8){b[0], b[1], b[2], b[3], 0, 0, 0, 0};
  return __builtin_amdgcn_mfma_f32_16x16x32_bf16(a8, b8, c, 0, 0, 0);
#endif
}
__device__ __forceinline__ void lds16(const u16* g, u16* l) {
  __builtin_amdgcn_global_load_lds(
      (const __attribute__((address_space(1))) void*)g,
      (__attribute__((address_space(3))) void*)l, 16, 0, 0);
}
// byte-level XOR swizzle: flips bits 4-6 (16B chunk idx) by row&7; involution.
__device__ __forceinline__ u32 swzb(u32 L) { return L ^ (((L >> 7) & 7) << 4); }

// ---- merged pre-pass: layernorm | weight transpose+cast | mask decode -----
// Block ranges (uniform branch on blockIdx.x):
//   [0,4096)      layernorm   [4096,8192) tcast   [8192,8208) mask
// Mask bias carries the softmax offset: valid -> -24, invalid -> -1e30.
__global__ __launch_bounds__(256) void k_pre(const float* __restrict__ x,
                                             const float* __restrict__ g_ln,
                                             const float* __restrict__ Wq,
                                             const float* __restrict__ Wkv,
                                             const float* __restrict__ Wo,
                                             const int* __restrict__ mraw,
                                             u16* __restrict__ xn,
                                             u16* __restrict__ Wt,
                                             u16* __restrict__ Wot,
                                             float* __restrict__ bias) {
  int bxg = blockIdx.x, tid = threadIdx.x;
  if (bxg < 4096) {
    int row = bxg;
    const float4 xv = *(const float4*)(x + (size_t)row * DIM_ + tid * 4);
    float s = xv.x + xv.y + xv.z + xv.w;
    float q = xv.x*xv.x + xv.y*xv.y + xv.z*xv.z + xv.w*xv.w;
    for (int off = 32; off; off >>= 1) { s += __shfl_xor(s, off); q += __shfl_xor(q, off); }
    __shared__ float red[8];
    int wave = tid >> 6, lane = tid & 63;
    if (lane == 0) { red[wave] = s; red[4 + wave] = q; }
    __syncthreads();
    s = red[0] + red[1] + red[2] + red[3];
    q = red[4] + red[5] + red[6] + red[7];
    float mu  = s * (1.0f / DIM_);
    float var = q * (1.0f / DIM_) - mu * mu;
    float inv = rsqrtf(var + 1e-5f);
    const float4 gv = *(const float4*)(g_ln + tid * 4);
    ushort4 ov;
    ov.x = f2bf((xv.x - mu) * inv * gv.x);
    ov.y = f2bf((xv.y - mu) * inv * gv.y);
    ov.z = f2bf((xv.z - mu) * inv * gv.z);
    ov.w = f2bf((xv.w - mu) * inv * gv.w);
    *(ushort4*)(xn + (size_t)row * DIM_ + tid * 4) = ov;
  } else if (bxg < 8192) {
    __shared__ float tile[32][33];
    int idx = bxg - 4096;
    int bx = idx & 127;
    int row0 = (idx >> 7) * 32;
    const float* in; u16* out; int ncols, cb;
    if (bx < 32)      { in = Wq;  out = Wt;               ncols = 1024; cb = bx; }
    else if (bx < 96) { in = Wkv; out = Wt + 1024 * 1024; ncols = 2048; cb = bx - 32; }
    else              { in = Wo;  out = Wot;              ncols = 1024; cb = bx - 96; }
    int tx = tid & 31, ty = tid >> 5;
    int col = cb * 32 + tx;
    for (int j = 0; j < 32; j += 8)
      tile[ty + j][tx] = in[(size_t)(row0 + ty + j) * ncols + col];
    __syncthreads();
    int orow = cb * 32 + ty;
    int ocol = row0 + tx;
    for (int j = 0; j < 32; j += 8)
      out[(size_t)(orow + j) * DIM_ + ocol] = f2bf(tile[tx][ty + j]);
  } else {
    __shared__ int flag;
    if (tid == 0) flag = 0;
    __syncthreads();
    int v = mraw[tid];
    if (v != 0 && v != 1) atomicOr(&flag, 1);
    __syncthreads();
    bool bytemode = (flag != 0);
    const unsigned char* mb = (const unsigned char*)mraw;
    int j = (bxg - 8192) * 256 + tid;
    bool valid = bytemode ? (mb[j] != 0) : (mraw[j] != 0);
    bias[j] = valid ? -24.0f : -1e30f;
  }
}

// ------------- GEMM C = A @ Bt^T, BK=64 double-buffer, opt fused RMS -------
// R21: K unrolled by 2 with two LDS buffer pairs -> stage both 32-wide
// sub-tiles under ONE barrier pair, compute both. Barriers per K=1024:
// 64 -> 32 (the 2-barrier structure's vmcnt-drain stall halves). LDS
// 16->32KB (QKV): occupancy bound is grid (3 blocks/CU), not LDS (5/CU),
// so unchanged. Accumulation order preserved (u=0 then u=1) -> bit-
// identical math. FUSE epilogue (R17-verified) unchanged.
template <int NF, bool OUT_BF16, bool FUSE>
__global__ __launch_bounds__(256) void k_gemm_bt(const u16* __restrict__ A,
                                                 const u16* __restrict__ Bt,
                                                 void* __restrict__ Cv,
                                                 const float* __restrict__ gq,
                                                 const float* __restrict__ gk,
                                                 u16* __restrict__ qo,
                                                 u16* __restrict__ ko,
                                                 int M, int Ncols, int K) {
  constexpr int BN = NF * 32;
  __shared__ u16 As[2][128 * 32];
  __shared__ u16 Bs[2][BN * 32];
  const int tid = threadIdx.x;
  const int wave = tid >> 6, lane = tid & 63;
  const int g = lane >> 4, li = lane & 15;
  const int gx = gridDim.x;
  const int wg = blockIdx.y * gx + blockIdx.x;
  const int per = (gx * gridDim.y) >> 3;
  const int swz = (wg & 7) * per + (wg >> 3);
  const int tm = (swz % gx) * 128, tn = (swz / gx) * BN;
  const int wm = (wave >> 1) * 64, wn = (wave & 1) * (NF * 16);
  const int srow = wave * 16 + (lane >> 2);
  const int scol = (lane & 3) * 8;

  f32x4 acc[4][NF];
#pragma unroll
  for (int i = 0; i < 4; ++i)
#pragma unroll
    for (int j = 0; j < NF; ++j) acc[i][j] = (f32x4){0.f, 0.f, 0.f, 0.f};

  const u16* ag = A  + (size_t)(tm + srow) * K + scol;
  const u16* bg = Bt + (size_t)(tn + srow) * K + scol;

  for (int k0 = 0; k0 < K; k0 += 64) {
    __syncthreads();                           // previous tiles' reads done
#pragma unroll
    for (int u = 0; u < 2; ++u) {
#pragma unroll
      for (int p = 0; p < 2; ++p)
        lds16(ag + (size_t)p * 64 * K + k0 + u * 32, &As[u][0] + p * 2048 + wave * 512);
#pragma unroll
      for (int p = 0; p < NF / 2; ++p)
        lds16(bg + (size_t)p * 64 * K + k0 + u * 32, &Bs[u][0] + p * 2048 + wave * 512);
    }
    __syncthreads();                           // staging visible (vmcnt drained)
#pragma unroll
    for (int u = 0; u < 2; ++u) {
      short8 af[4], bfm[NF];
#pragma unroll
      for (int m = 0; m < 4; ++m) af[m]  = ld8(&As[u][0] + (wm + m * 16 + li) * 32 + g * 8);
#pragma unroll
      for (int n = 0; n < NF; ++n) bfm[n] = ld8(&Bs[u][0] + (wn + n * 16 + li) * 32 + g * 8);
#pragma unroll
      for (int m = 0; m < 4; ++m)
#pragma unroll
        for (int n = 0; n < NF; ++n)
          acc[m][n] = mfma16(af[m], bfm[n], acc[m][n]);
    }
  }

  if constexpr (FUSE) {
    const int colbase = tn + wn;          // multiple of 64 (wave-uniform)
    const int region = colbase >> 10;     // 0=q 1=k 2=v
    if (region < 2) {
      const int h = (colbase & 1023) >> 6;
      const float* gam = (region == 0) ? gq : gk;
      u16* dst = (region == 0) ? qo : ko;
#pragma unroll
      for (int m = 0; m < 4; ++m)
#pragma unroll
        for (int r = 0; r < 4; ++r) {
          float ss = 0.f;
#pragma unroll
          for (int n = 0; n < NF; ++n) ss += acc[m][n][r] * acc[m][n][r];
          ss += __shfl_xor(ss, 1);
          ss += __shfl_xor(ss, 2);
          ss += __shfl_xor(ss, 4);
          ss += __shfl_xor(ss, 8);
          float scale = 8.0f / fmaxf(sqrtf(ss), 1e-12f);   // sqrt(64)=8
          int row = tm + wm + m * 16 + g * 4 + r;
          int bb = row >> 11, nn = row & 2047;
          u16* drow = dst + (((size_t)(bb * H_ + h)) * N_ + nn) * 64;
#pragma unroll
          for (int n = 0; n < NF; ++n) {
            int d = n * 16 + li;
            drow[d] = f2bf(acc[m][n][r] * scale * gam[h * 64 + d]);
          }
        }
      return;
    }
    // V columns: bf16 into Cq (layout unchanged, consumed by k_vt)
#pragma unroll
    for (int m = 0; m < 4; ++m)
#pragma unroll
      for (int n = 0; n < NF; ++n) {
        int row = tm + wm + m * 16 + g * 4;
        int col = tn + wn + n * 16 + li;
#pragma unroll
        for (int r = 0; r < 4; ++r)
          ((u16*)Cv)[(size_t)(row + r) * Ncols + col] = f2bf(acc[m][n][r]);
      }
    return;
  }

#pragma unroll
  for (int m = 0; m < 4; ++m)
#pragma unroll
    for (int n = 0; n < NF; ++n) {
      int row = tm + wm + m * 16 + g * 4;
      int col = tn + wn + n * 16 + li;
#pragma unroll
      for (int r = 0; r < 4; ++r) {
        float v = acc[m][n][r];
        if (OUT_BF16) ((u16*)Cv)[(size_t)(row + r) * Ncols + col] = f2bf(v);
        else          ((float*)Cv)[(size_t)(row + r) * Ncols + col] = v;
      }
    }
}

// ------------- V relayout (identity cols): -> vT [b*h][d][n] ---------------
__global__ __launch_bounds__(256) void k_vt(const u16* __restrict__ Cq,
                                            u16* __restrict__ vT) {
  __shared__ float tile[64][65];
  int bh = blockIdx.y;
  int b = bh >> 4, h = bh & 15;
  int n0 = blockIdx.x * 64;
  int tx = threadIdx.x, ty = threadIdx.y;
  for (int i = 0; i < 64; i += 4) {
    int n = n0 + ty + i;
    tile[ty + i][tx] = bf2f(Cq[((size_t)(b * N_ + n)) * E3_ + 2048 + h * 64 + tx]);
  }
  __syncthreads();
  u16* dst = vT + (size_t)bh * 64 * N_;
  for (int i = 0; i < 64; i += 4) {
    int d = ty + i;
    dst[(size_t)d * N_ + n0 + tx] = f2bf(tile[tx][d]);
  }
}

// ------------- flash attention: R20-exact (passing, 61us) ------------------
__global__ __launch_bounds__(256, 2) void k_attn(const u16* __restrict__ Q,
                                                 const u16* __restrict__ K,
                                                 const u16* __restrict__ Vt,
                                                 const float* __restrict__ bias,
                                                 u16* __restrict__ Out) {
  __shared__ u16 Ks[2][4096];           // 16 KB
  __shared__ u16 Vs[2][4096];           // 16 KB
  int wg = blockIdx.x;
  int xcd = wg & 7, slot = wg >> 3;     // slot 0..63
  int bh = xcd * 4 + (slot & 3);        // bijective: 8 xcd x 4 bh x 16 qchunk
  int qb = (slot >> 2) * 128;           // 16 chunks x 128 q = 2048
  int b = bh >> 4, h = bh & 15;
  int tid = threadIdx.x, wave = tid >> 6, lane = tid & 63;
  int g = lane >> 4, li = lane & 15;
  const u16* Qh = Q  + (size_t)bh * N_ * 64;
  const u16* Kh = K  + (size_t)bh * N_ * 64;
  const u16* Vh = Vt + (size_t)bh * 64 * N_;
  const float* bg = bias + b * N_;

  // staging addresses: 2 chunks of 16B per tile per thread (256 thr x 32B = 8KB)
  u32 Ls[2], kS[2], vR[2], vC[2];
#pragma unroll
  for (int s = 0; s < 2; ++s) {
    Ls[s] = tid * 16 + s * 4096;
    kS[s] = swzb(Ls[s]) >> 1;
    vR[s] = Ls[s] >> 7;
    vC[s] = (swzb(Ls[s]) & 127) >> 1;
  }

  int qr0 = qb + wave * 32 + li;        // q-subgroup A
  int qr1 = qr0 + 16;                   // q-subgroup B
  short8 aqA0 = ld8(Qh + (size_t)qr0 * 64 + g * 8);
  short8 aqA1 = ld8(Qh + (size_t)qr0 * 64 + 32 + g * 8);
  short8 aqB0 = ld8(Qh + (size_t)qr1 * 64 + g * 8);
  short8 aqB1 = ld8(Qh + (size_t)qr1 * 64 + 32 + g * 8);

  f32x4 oTA[4], oTB[4];
#pragma unroll
  for (int dc = 0; dc < 4; ++dc) {
    oTA[dc] = (f32x4){0.f, 0.f, 0.f, 0.f};
    oTB[dc] = (f32x4){0.f, 0.f, 0.f, 0.f};
  }
  float lA = 0.f, lB = 0.f;

  const int fsw  = 8 * (g ^ (li & 7));
  const int fsw2 = fsw ^ 32;
  const int vbl = li * 64 + (g & 1) * 4;
  int vsw[4];
#pragma unroll
  for (int c = 0; c < 4; ++c)
    vsw[c] = (((2 * c + (g >> 1)) ^ (li & 7)) << 3);

  // prologue: stage tile 0 into buffer 0
#pragma unroll
  for (int s = 0; s < 2; ++s) {
    lds16(Kh + kS[s], &Ks[0][0] + (Ls[s] >> 1));
    lds16(Vh + (size_t)vR[s] * N_ + vC[s], &Vs[0][0] + (Ls[s] >> 1));
  }
  __syncthreads();

  for (int kt = 0; kt < 32; ++kt) {
    int cur = kt & 1;
    int kbase = kt * 64;
    if (kt < 31) {                       // stage next tile (async, no regs)
      int nxt = cur ^ 1;
      int nb = kbase + 64;
#pragma unroll
      for (int s = 0; s < 2; ++s) {
        lds16(Kh + (size_t)nb * 64 + kS[s], &Ks[nxt][0] + (Ls[s] >> 1));
        lds16(Vh + (size_t)vR[s] * N_ + nb + vC[s], &Vs[nxt][0] + (Ls[s] >> 1));
      }
    }
    // bias (includes -24 offset) for current tile: 4x broadcast float4
    float4 bbc[4];
#pragma unroll
    for (int c = 0; c < 4; ++c)
      bbc[c] = *(const float4*)&bg[kbase + c * 16 + g * 4];
    const u16* Kb = &Ks[cur][0];
    const u16* Vb = &Vs[cur][0];
    // ---- S^T = mfma(K, Q, C=bias-24) for both q-groups ------------------
    f32x4 stA[4], stB[4];
    __builtin_amdgcn_s_setprio(1);
#pragma unroll
    for (int c = 0; c < 4; ++c) {
      int rb = (c * 16 + li) * 64;
      short8 kf0 = ld8(Kb + rb + fsw);
      short8 kf1 = ld8(Kb + rb + fsw2);
      f32x4 z = (f32x4){bbc[c].x, bbc[c].y, bbc[c].z, bbc[c].w};
      stA[c] = mfma16(kf1, aqA1, mfma16(kf0, aqA0, z));
      stB[c] = mfma16(kf1, aqB1, mfma16(kf0, aqB0, z));
    }
    __builtin_amdgcn_s_setprio(0);
    // ---- V-frags (b64 reads), shared by both q-groups -------------------
    short4v vf16[4][4];
#pragma unroll
    for (int dc = 0; dc < 4; ++dc)
#pragma unroll
      for (int c = 0; c < 4; ++c)
        vf16[dc][c] = *(const short4v*)(Vb + dc * 1024 + vbl + vsw[c]);
    // ---- softmax A: P = exp(S + bias), offset pre-folded ----------------
    float pvA[4][4], csA[4];
#pragma unroll
    for (int c = 0; c < 4; ++c) {
#pragma unroll
      for (int r = 0; r < 4; ++r) pvA[c][r] = __expf(stA[c][r]);
      csA[c] = (pvA[c][0] + pvA[c][1]) + (pvA[c][2] + pvA[c][3]);
    }
    float rsA = (csA[0] + csA[1]) + (csA[2] + csA[3]);
    rsA += __shfl_xor(rsA, 16);
    rsA += __shfl_xor(rsA, 32);
    lA += rsA;
    // ---- softmax B -------------------------------------------------------
    float pvB[4][4], csB[4];
#pragma unroll
    for (int c = 0; c < 4; ++c) {
#pragma unroll
      for (int r = 0; r < 4; ++r) pvB[c][r] = __expf(stB[c][r]);
      csB[c] = (pvB[c][0] + pvB[c][1]) + (pvB[c][2] + pvB[c][3]);
    }
    float rsB = (csB[0] + csB[1]) + (csB[2] + csB[3]);
    rsB += __shfl_xor(rsB, 16);
    rsB += __shfl_xor(rsB, 32);
    lB += rsB;
    // ---- pack P (both groups) via v_cvt_pk_bf16_f32 ----------------------
    union { u32 u2[2]; short4v s4; } pbA[4], pbB[4];
#pragma unroll
    for (int c = 0; c < 4; ++c) {
      asm("v_cvt_pk_bf16_f32 %0, %1, %2" : "=v"(pbA[c].u2[0]) : "v"(pvA[c][0]), "v"(pvA[c][1]));
      asm("v_cvt_pk_bf16_f32 %0, %1, %2" : "=v"(pbA[c].u2[1]) : "v"(pvA[c][2]), "v"(pvA[c][3]));
      asm("v_cvt_pk_bf16_f32 %0, %1, %2" : "=v"(pbB[c].u2[0]) : "v"(pvB[c][0]), "v"(pvB[c][1]));
      asm("v_cvt_pk_bf16_f32 %0, %1, %2" : "=v"(pbB[c].u2[1]) : "v"(pvB[c][2]), "v"(pvB[c][3]));
    }
    // ---- PV: V-frag (A operand) shared, B operand per q-group -----------
    __builtin_amdgcn_s_setprio(1);
#pragma unroll
    for (int dc = 0; dc < 4; ++dc)
#pragma unroll
      for (int c = 0; c < 4; ++c) {
        oTA[dc] = mfma16k16(vf16[dc][c], pbA[c].s4, oTA[dc]);
        oTB[dc] = mfma16k16(vf16[dc][c], pbB[c].s4, oTB[dc]);
      }
    __builtin_amdgcn_s_setprio(0);
    __syncthreads();                    // next-tile staging complete + buf free
  }

  float invA = 1.0f / lA, invB = 1.0f / lB;
#pragma unroll
  for (int dc = 0; dc < 4; ++dc) {
    ushort4 ovA, ovB;
    ovA.x = f2bf(oTA[dc][0] * invA); ovA.y = f2bf(oTA[dc][1] * invA);
    ovA.z = f2bf(oTA[dc][2] * invA); ovA.w = f2bf(oTA[dc][3] * invA);
    ovB.x = f2bf(oTB[dc][0] * invB); ovB.y = f2bf(oTB[dc][1] * invB);
    ovB.z = f2bf(oTB[dc][2] * invB); ovB.w = f2bf(oTB[dc][3] * invB);
    *(ushort4*)&Out[((size_t)(b * N_ + qr0)) * DIM_ + h * 64 + dc * 16 + g * 4] = ovA;
    *(ushort4*)&Out[((size_t)(b * N_ + qr1)) * DIM_ + h * 64 + dc * 16 + g * 4] = ovB;
  }
}

// ---------------------------------------------------------------------------
extern "C" void kernel_launch(void* const* d_in, const int* in_sizes, int n_in,
                              void* d_out, int out_size, void* d_ws, size_t ws_size,
                              hipStream_t stream) {
  const float* x    = (const float*)d_in[0];
  const int*   mask = (const int*)d_in[1];
  const float* g_ln = (const float*)d_in[2];
  const float* g_q  = (const float*)d_in[3];
  const float* g_k  = (const float*)d_in[4];
  const float* Wq   = (const float*)d_in[5];
  const float* Wkv  = (const float*)d_in[6];
  const float* Wo   = (const float*)d_in[7];
  float* out = (float*)d_out;

  char* ws = (char*)d_ws;
  u16*   xn   = (u16*)(ws);                         // 8 MB
  u16*   Wt   = (u16*)(ws + 8388608);               // 6 MB  (Wq^T | Wkv^T) [3072][1024]
  u16*   Wot  = (u16*)(ws + 14680064);              // 2 MB  Wo^T [1024][1024]
  float* bias = (float*)(ws + 16777216);            // 16 KB
  u16*   Cq   = (u16*)(ws + 16793600);              // 24 MB [4096][3072] (V third used)
  u16*   qb   = (u16*)(ws + 41959424);              // 8 MB [b,h,n,d]
  u16*   kb   = (u16*)(ws + 41959424 + 8388608);    // 8 MB
  u16*   vT   = (u16*)(ws + 41959424 + 2*8388608);  // 8 MB [b*h][d][n]
  u16*   ao   = (u16*)(ws + 41959424 + 3*8388608);  // 8 MB [4096][1024]

  k_pre<<<8208, 256, 0, stream>>>(x, g_ln, Wq, Wkv, Wo, mask, xn, Wt, Wot, bias);
  k_gemm_bt<4, true, true><<<dim3(32, 24), 256, 0, stream>>>(
      xn, Wt, Cq, g_q, g_k, qb, kb, ROWS_, E3_, DIM_);
  k_vt<<<dim3(32, 32), dim3(64, 4), 0, stream>>>(Cq, vT);
  k_attn<<<512, 256, 0, stream>>>(qb, kb, vT, bias, ao);
  k_gemm_bt<2, false, false><<<dim3(32, 16), 256, 0, stream>>>(
      ao, Wot, out, nullptr, nullptr, nullptr, nullptr, ROWS_, DIM_, DIM_);
}

// Round 22
// 134.806 us; speedup vs baseline: 1.0471x; 1.0471x over previous
//
#include <hip/hip_runtime.h>

using u16 = unsigned short;
using u32 = unsigned int;

#define B_   2
#define N_   2048
#define DIM_ 1024
#define H_   16
#define D_   64
#define ROWS_ (B_*N_)   // 4096
#define E3_  3072       // q|k|v concatenated

typedef __attribute__((ext_vector_type(8))) short short8;
typedef __attribute__((ext_vector_type(4))) short short4v;
typedef __attribute__((ext_vector_type(4))) float f32x4;

__device__ __forceinline__ u16 f2bf(float f) {
  u32 u = __builtin_bit_cast(u32, f);
  u32 r = (u + 0x7FFFu + ((u >> 16) & 1u)) >> 16;
  return (u16)r;
}
__device__ __forceinline__ float bf2f(u16 h) {
  u32 u = ((u32)h) << 16;
  return __builtin_bit_cast(float, u);
}
__device__ __forceinline__ short8 ld8(const u16* p) { return *(const short8*)p; }
__device__ __forceinline__ f32x4 mfma16(short8 a, short8 b, f32x4 c) {
  return __builtin_amdgcn_mfma_f32_16x16x32_bf16(a, b, c, 0, 0, 0);
}
// K=16 bf16 MFMA (R9-verified): B[k=g*4+j][col=li] == softmax's in-lane P.
__device__ __forceinline__ f32x4 mfma16k16(short4v a, short4v b, f32x4 c) {
#if !defined(__HIP_DEVICE_COMPILE__)
  (void)a; (void)b;
  return c;
#elif __has_builtin(__builtin_amdgcn_mfma_f32_16x16x16bf16_1k)
  return __builtin_amdgcn_mfma_f32_16x16x16bf16_1k(a, b, c, 0, 0, 0);
#else
  short8 a8 = (short8){a[0], a[1], a[2], a[3], 0, 0, 0, 0};
  short8 b8 = (short8){b[0], b[1], b[2], b[3], 0, 0, 0, 0};
  return __builtin_amdgcn_mfma_f32_16x16x32_bf16(a8, b8, c, 0, 0, 0);
#endif
}
__device__ __forceinline__ void lds16(const u16* g, u16* l) {
  __builtin_amdgcn_global_load_lds(
      (const __attribute__((address_space(1))) void*)g,
      (__attribute__((address_space(3))) void*)l, 16, 0, 0);
}
// byte-level XOR swizzle: flips bits 4-6 (16B chunk idx) by row&7; involution.
__device__ __forceinline__ u32 swzb(u32 L) { return L ^ (((L >> 7) & 7) << 4); }

// ---- merged pre-pass: layernorm | weight transpose+cast | mask decode -----
// Block ranges (uniform branch on blockIdx.x):
//   [0,4096)      layernorm   [4096,8192) tcast   [8192,8208) mask
// Mask bias carries the softmax offset: valid -> -24, invalid -> -1e30.
__global__ __launch_bounds__(256) void k_pre(const float* __restrict__ x,
                                             const float* __restrict__ g_ln,
                                             const float* __restrict__ Wq,
                                             const float* __restrict__ Wkv,
                                             const float* __restrict__ Wo,
                                             const int* __restrict__ mraw,
                                             u16* __restrict__ xn,
                                             u16* __restrict__ Wt,
                                             u16* __restrict__ Wot,
                                             float* __restrict__ bias) {
  int bxg = blockIdx.x, tid = threadIdx.x;
  if (bxg < 4096) {
    int row = bxg;
    const float4 xv = *(const float4*)(x + (size_t)row * DIM_ + tid * 4);
    float s = xv.x + xv.y + xv.z + xv.w;
    float q = xv.x*xv.x + xv.y*xv.y + xv.z*xv.z + xv.w*xv.w;
    for (int off = 32; off; off >>= 1) { s += __shfl_xor(s, off); q += __shfl_xor(q, off); }
    __shared__ float red[8];
    int wave = tid >> 6, lane = tid & 63;
    if (lane == 0) { red[wave] = s; red[4 + wave] = q; }
    __syncthreads();
    s = red[0] + red[1] + red[2] + red[3];
    q = red[4] + red[5] + red[6] + red[7];
    float mu  = s * (1.0f / DIM_);
    float var = q * (1.0f / DIM_) - mu * mu;
    float inv = rsqrtf(var + 1e-5f);
    const float4 gv = *(const float4*)(g_ln + tid * 4);
    ushort4 ov;
    ov.x = f2bf((xv.x - mu) * inv * gv.x);
    ov.y = f2bf((xv.y - mu) * inv * gv.y);
    ov.z = f2bf((xv.z - mu) * inv * gv.z);
    ov.w = f2bf((xv.w - mu) * inv * gv.w);
    *(ushort4*)(xn + (size_t)row * DIM_ + tid * 4) = ov;
  } else if (bxg < 8192) {
    __shared__ float tile[32][33];
    int idx = bxg - 4096;
    int bx = idx & 127;
    int row0 = (idx >> 7) * 32;
    const float* in; u16* out; int ncols, cb;
    if (bx < 32)      { in = Wq;  out = Wt;               ncols = 1024; cb = bx; }
    else if (bx < 96) { in = Wkv; out = Wt + 1024 * 1024; ncols = 2048; cb = bx - 32; }
    else              { in = Wo;  out = Wot;              ncols = 1024; cb = bx - 96; }
    int tx = tid & 31, ty = tid >> 5;
    int col = cb * 32 + tx;
    for (int j = 0; j < 32; j += 8)
      tile[ty + j][tx] = in[(size_t)(row0 + ty + j) * ncols + col];
    __syncthreads();
    int orow = cb * 32 + ty;
    int ocol = row0 + tx;
    for (int j = 0; j < 32; j += 8)
      out[(size_t)(orow + j) * DIM_ + ocol] = f2bf(tile[tx][ty + j]);
  } else {
    __shared__ int flag;
    if (tid == 0) flag = 0;
    __syncthreads();
    int v = mraw[tid];
    if (v != 0 && v != 1) atomicOr(&flag, 1);
    __syncthreads();
    bool bytemode = (flag != 0);
    const unsigned char* mb = (const unsigned char*)mraw;
    int j = (bxg - 8192) * 256 + tid;
    bool valid = bytemode ? (mb[j] != 0) : (mraw[j] != 0);
    bias[j] = valid ? -24.0f : -1e30f;
  }
}

// ------------- GEMM C = A @ Bt^T (R20 BK=32 form), opt fused RMS -----------
// R21's BK=64 variant REGRESSED (+7us): the vmcnt-drain stall scales with
// in-flight staging per barrier, not barrier count. This is the R20-exact
// 2-barrier BK=32 structure. FUSE epilogue (R17-verified) unchanged.
template <int NF, bool OUT_BF16, bool FUSE>
__global__ __launch_bounds__(256) void k_gemm_bt(const u16* __restrict__ A,
                                                 const u16* __restrict__ Bt,
                                                 void* __restrict__ Cv,
                                                 const float* __restrict__ gq,
                                                 const float* __restrict__ gk,
                                                 u16* __restrict__ qo,
                                                 u16* __restrict__ ko,
                                                 int M, int Ncols, int K) {
  constexpr int BN = NF * 32;
  __shared__ u16 As[128 * 32];
  __shared__ u16 Bs[BN * 32];
  const int tid = threadIdx.x;
  const int wave = tid >> 6, lane = tid & 63;
  const int g = lane >> 4, li = lane & 15;
  const int gx = gridDim.x;
  const int wg = blockIdx.y * gx + blockIdx.x;
  const int per = (gx * gridDim.y) >> 3;
  const int swz = (wg & 7) * per + (wg >> 3);
  const int tm = (swz % gx) * 128, tn = (swz / gx) * BN;
  const int wm = (wave >> 1) * 64, wn = (wave & 1) * (NF * 16);
  const int srow = wave * 16 + (lane >> 2);
  const int scol = (lane & 3) * 8;

  f32x4 acc[4][NF];
#pragma unroll
  for (int i = 0; i < 4; ++i)
#pragma unroll
    for (int j = 0; j < NF; ++j) acc[i][j] = (f32x4){0.f, 0.f, 0.f, 0.f};

  const u16* ag = A  + (size_t)(tm + srow) * K + scol;
  const u16* bg = Bt + (size_t)(tn + srow) * K + scol;

  for (int k0 = 0; k0 < K; k0 += 32) {
    __syncthreads();
#pragma unroll
    for (int p = 0; p < 2; ++p)
      lds16(ag + (size_t)p * 64 * K + k0, As + p * 2048 + wave * 512);
#pragma unroll
    for (int p = 0; p < NF / 2; ++p)
      lds16(bg + (size_t)p * 64 * K + k0, Bs + p * 2048 + wave * 512);
    __syncthreads();
    short8 af[4], bfm[NF];
#pragma unroll
    for (int m = 0; m < 4; ++m) af[m]  = ld8(As + (wm + m * 16 + li) * 32 + g * 8);
#pragma unroll
    for (int n = 0; n < NF; ++n) bfm[n] = ld8(Bs + (wn + n * 16 + li) * 32 + g * 8);
#pragma unroll
    for (int m = 0; m < 4; ++m)
#pragma unroll
      for (int n = 0; n < NF; ++n)
        acc[m][n] = mfma16(af[m], bfm[n], acc[m][n]);
  }

  if constexpr (FUSE) {
    const int colbase = tn + wn;          // multiple of 64 (wave-uniform)
    const int region = colbase >> 10;     // 0=q 1=k 2=v
    if (region < 2) {
      const int h = (colbase & 1023) >> 6;
      const float* gam = (region == 0) ? gq : gk;
      u16* dst = (region == 0) ? qo : ko;
#pragma unroll
      for (int m = 0; m < 4; ++m)
#pragma unroll
        for (int r = 0; r < 4; ++r) {
          float ss = 0.f;
#pragma unroll
          for (int n = 0; n < NF; ++n) ss += acc[m][n][r] * acc[m][n][r];
          ss += __shfl_xor(ss, 1);
          ss += __shfl_xor(ss, 2);
          ss += __shfl_xor(ss, 4);
          ss += __shfl_xor(ss, 8);
          float scale = 8.0f / fmaxf(sqrtf(ss), 1e-12f);   // sqrt(64)=8
          int row = tm + wm + m * 16 + g * 4 + r;
          int bb = row >> 11, nn = row & 2047;
          u16* drow = dst + (((size_t)(bb * H_ + h)) * N_ + nn) * 64;
#pragma unroll
          for (int n = 0; n < NF; ++n) {
            int d = n * 16 + li;
            drow[d] = f2bf(acc[m][n][r] * scale * gam[h * 64 + d]);
          }
        }
      return;
    }
    // V columns: bf16 into Cq (layout unchanged, consumed by k_vt)
#pragma unroll
    for (int m = 0; m < 4; ++m)
#pragma unroll
      for (int n = 0; n < NF; ++n) {
        int row = tm + wm + m * 16 + g * 4;
        int col = tn + wn + n * 16 + li;
#pragma unroll
        for (int r = 0; r < 4; ++r)
          ((u16*)Cv)[(size_t)(row + r) * Ncols + col] = f2bf(acc[m][n][r]);
      }
    return;
  }

#pragma unroll
  for (int m = 0; m < 4; ++m)
#pragma unroll
    for (int n = 0; n < NF; ++n) {
      int row = tm + wm + m * 16 + g * 4;
      int col = tn + wn + n * 16 + li;
#pragma unroll
      for (int r = 0; r < 4; ++r) {
        float v = acc[m][n][r];
        if (OUT_BF16) ((u16*)Cv)[(size_t)(row + r) * Ncols + col] = f2bf(v);
        else          ((float*)Cv)[(size_t)(row + r) * Ncols + col] = v;
      }
    }
}

// ------------- V relayout (identity cols): -> vT [b*h][d][n] ---------------
__global__ __launch_bounds__(256) void k_vt(const u16* __restrict__ Cq,
                                            u16* __restrict__ vT) {
  __shared__ float tile[64][65];
  int bh = blockIdx.y;
  int b = bh >> 4, h = bh & 15;
  int n0 = blockIdx.x * 64;
  int tx = threadIdx.x, ty = threadIdx.y;
  for (int i = 0; i < 64; i += 4) {
    int n = n0 + ty + i;
    tile[ty + i][tx] = bf2f(Cq[((size_t)(b * N_ + n)) * E3_ + 2048 + h * 64 + tx]);
  }
  __syncthreads();
  u16* dst = vT + (size_t)bh * 64 * N_;
  for (int i = 0; i < 64; i += 4) {
    int d = ty + i;
    dst[(size_t)d * N_ + n0 + tx] = f2bf(tile[tx][d]);
  }
}

// ------------- flash attention: R20-exact (passing, 61us) ------------------
// Fixed-offset softmax (offset folded into bias), 128 q per block, LDS-
// staged K/V via global_load_lds (double-buffered, XOR-swizzled),
// exchange-free K=16 PV.
__global__ __launch_bounds__(256, 2) void k_attn(const u16* __restrict__ Q,
                                                 const u16* __restrict__ K,
                                                 const u16* __restrict__ Vt,
                                                 const float* __restrict__ bias,
                                                 u16* __restrict__ Out) {
  __shared__ u16 Ks[2][4096];           // 16 KB
  __shared__ u16 Vs[2][4096];           // 16 KB
  int wg = blockIdx.x;
  int xcd = wg & 7, slot = wg >> 3;     // slot 0..63
  int bh = xcd * 4 + (slot & 3);        // bijective: 8 xcd x 4 bh x 16 qchunk
  int qb = (slot >> 2) * 128;           // 16 chunks x 128 q = 2048
  int b = bh >> 4, h = bh & 15;
  int tid = threadIdx.x, wave = tid >> 6, lane = tid & 63;
  int g = lane >> 4, li = lane & 15;
  const u16* Qh = Q  + (size_t)bh * N_ * 64;
  const u16* Kh = K  + (size_t)bh * N_ * 64;
  const u16* Vh = Vt + (size_t)bh * 64 * N_;
  const float* bg = bias + b * N_;

  // staging addresses: 2 chunks of 16B per tile per thread (256 thr x 32B = 8KB)
  u32 Ls[2], kS[2], vR[2], vC[2];
#pragma unroll
  for (int s = 0; s < 2; ++s) {
    Ls[s] = tid * 16 + s * 4096;
    kS[s] = swzb(Ls[s]) >> 1;
    vR[s] = Ls[s] >> 7;
    vC[s] = (swzb(Ls[s]) & 127) >> 1;
  }

  int qr0 = qb + wave * 32 + li;        // q-subgroup A
  int qr1 = qr0 + 16;                   // q-subgroup B
  short8 aqA0 = ld8(Qh + (size_t)qr0 * 64 + g * 8);
  short8 aqA1 = ld8(Qh + (size_t)qr0 * 64 + 32 + g * 8);
  short8 aqB0 = ld8(Qh + (size_t)qr1 * 64 + g * 8);
  short8 aqB1 = ld8(Qh + (size_t)qr1 * 64 + 32 + g * 8);

  f32x4 oTA[4], oTB[4];
#pragma unroll
  for (int dc = 0; dc < 4; ++dc) {
    oTA[dc] = (f32x4){0.f, 0.f, 0.f, 0.f};
    oTB[dc] = (f32x4){0.f, 0.f, 0.f, 0.f};
  }
  float lA = 0.f, lB = 0.f;

  const int fsw  = 8 * (g ^ (li & 7));
  const int fsw2 = fsw ^ 32;
  const int vbl = li * 64 + (g & 1) * 4;
  int vsw[4];
#pragma unroll
  for (int c = 0; c < 4; ++c)
    vsw[c] = (((2 * c + (g >> 1)) ^ (li & 7)) << 3);

  // prologue: stage tile 0 into buffer 0
#pragma unroll
  for (int s = 0; s < 2; ++s) {
    lds16(Kh + kS[s], &Ks[0][0] + (Ls[s] >> 1));
    lds16(Vh + (size_t)vR[s] * N_ + vC[s], &Vs[0][0] + (Ls[s] >> 1));
  }
  __syncthreads();

  for (int kt = 0; kt < 32; ++kt) {
    int cur = kt & 1;
    int kbase = kt * 64;
    if (kt < 31) {                       // stage next tile (async, no regs)
      int nxt = cur ^ 1;
      int nb = kbase + 64;
#pragma unroll
      for (int s = 0; s < 2; ++s) {
        lds16(Kh + (size_t)nb * 64 + kS[s], &Ks[nxt][0] + (Ls[s] >> 1));
        lds16(Vh + (size_t)vR[s] * N_ + nb + vC[s], &Vs[nxt][0] + (Ls[s] >> 1));
      }
    }
    // bias (includes -24 offset) for current tile: 4x broadcast float4
    float4 bbc[4];
#pragma unroll
    for (int c = 0; c < 4; ++c)
      bbc[c] = *(const float4*)&bg[kbase + c * 16 + g * 4];
    const u16* Kb = &Ks[cur][0];
    const u16* Vb = &Vs[cur][0];
    // ---- S^T = mfma(K, Q, C=bias-24) for both q-groups ------------------
    f32x4 stA[4], stB[4];
    __builtin_amdgcn_s_setprio(1);
#pragma unroll
    for (int c = 0; c < 4; ++c) {
      int rb = (c * 16 + li) * 64;
      short8 kf0 = ld8(Kb + rb + fsw);
      short8 kf1 = ld8(Kb + rb + fsw2);
      f32x4 z = (f32x4){bbc[c].x, bbc[c].y, bbc[c].z, bbc[c].w};
      stA[c] = mfma16(kf1, aqA1, mfma16(kf0, aqA0, z));
      stB[c] = mfma16(kf1, aqB1, mfma16(kf0, aqB0, z));
    }
    __builtin_amdgcn_s_setprio(0);
    // ---- V-frags (b64 reads), shared by both q-groups -------------------
    short4v vf16[4][4];
#pragma unroll
    for (int dc = 0; dc < 4; ++dc)
#pragma unroll
      for (int c = 0; c < 4; ++c)
        vf16[dc][c] = *(const short4v*)(Vb + dc * 1024 + vbl + vsw[c]);
    // ---- softmax A: P = exp(S + bias), offset pre-folded ----------------
    float pvA[4][4], csA[4];
#pragma unroll
    for (int c = 0; c < 4; ++c) {
#pragma unroll
      for (int r = 0; r < 4; ++r) pvA[c][r] = __expf(stA[c][r]);
      csA[c] = (pvA[c][0] + pvA[c][1]) + (pvA[c][2] + pvA[c][3]);
    }
    float rsA = (csA[0] + csA[1]) + (csA[2] + csA[3]);
    rsA += __shfl_xor(rsA, 16);
    rsA += __shfl_xor(rsA, 32);
    lA += rsA;
    // ---- softmax B -------------------------------------------------------
    float pvB[4][4], csB[4];
#pragma unroll
    for (int c = 0; c < 4; ++c) {
#pragma unroll
      for (int r = 0; r < 4; ++r) pvB[c][r] = __expf(stB[c][r]);
      csB[c] = (pvB[c][0] + pvB[c][1]) + (pvB[c][2] + pvB[c][3]);
    }
    float rsB = (csB[0] + csB[1]) + (csB[2] + csB[3]);
    rsB += __shfl_xor(rsB, 16);
    rsB += __shfl_xor(rsB, 32);
    lB += rsB;
    // ---- pack P (both groups) via v_cvt_pk_bf16_f32 ----------------------
    union { u32 u2[2]; short4v s4; } pbA[4], pbB[4];
#pragma unroll
    for (int c = 0; c < 4; ++c) {
      asm("v_cvt_pk_bf16_f32 %0, %1, %2" : "=v"(pbA[c].u2[0]) : "v"(pvA[c][0]), "v"(pvA[c][1]));
      asm("v_cvt_pk_bf16_f32 %0, %1, %2" : "=v"(pbA[c].u2[1]) : "v"(pvA[c][2]), "v"(pvA[c][3]));
      asm("v_cvt_pk_bf16_f32 %0, %1, %2" : "=v"(pbB[c].u2[0]) : "v"(pvB[c][0]), "v"(pvB[c][1]));
      asm("v_cvt_pk_bf16_f32 %0, %1, %2" : "=v"(pbB[c].u2[1]) : "v"(pvB[c][2]), "v"(pvB[c][3]));
    }
    // ---- PV: V-frag (A operand) shared, B operand per q-group -----------
    __builtin_amdgcn_s_setprio(1);
#pragma unroll
    for (int dc = 0; dc < 4; ++dc)
#pragma unroll
      for (int c = 0; c < 4; ++c) {
        oTA[dc] = mfma16k16(vf16[dc][c], pbA[c].s4, oTA[dc]);
        oTB[dc] = mfma16k16(vf16[dc][c], pbB[c].s4, oTB[dc]);
      }
    __builtin_amdgcn_s_setprio(0);
    __syncthreads();                    // next-tile staging complete + buf free
  }

  float invA = 1.0f / lA, invB = 1.0f / lB;
#pragma unroll
  for (int dc = 0; dc < 4; ++dc) {
    ushort4 ovA, ovB;
    ovA.x = f2bf(oTA[dc][0] * invA); ovA.y = f2bf(oTA[dc][1] * invA);
    ovA.z = f2bf(oTA[dc][2] * invA); ovA.w = f2bf(oTA[dc][3] * invA);
    ovB.x = f2bf(oTB[dc][0] * invB); ovB.y = f2bf(oTB[dc][1] * invB);
    ovB.z = f2bf(oTB[dc][2] * invB); ovB.w = f2bf(oTB[dc][3] * invB);
    *(ushort4*)&Out[((size_t)(b * N_ + qr0)) * DIM_ + h * 64 + dc * 16 + g * 4] = ovA;
    *(ushort4*)&Out[((size_t)(b * N_ + qr1)) * DIM_ + h * 64 + dc * 16 + g * 4] = ovB;
  }
}

// ---------------------------------------------------------------------------
extern "C" void kernel_launch(void* const* d_in, const int* in_sizes, int n_in,
                              void* d_out, int out_size, void* d_ws, size_t ws_size,
                              hipStream_t stream) {
  const float* x    = (const float*)d_in[0];
  const int*   mask = (const int*)d_in[1];
  const float* g_ln = (const float*)d_in[2];
  const float* g_q  = (const float*)d_in[3];
  const float* g_k  = (const float*)d_in[4];
  const float* Wq   = (const float*)d_in[5];
  const float* Wkv  = (const float*)d_in[6];
  const float* Wo   = (const float*)d_in[7];
  float* out = (float*)d_out;

  char* ws = (char*)d_ws;
  u16*   xn   = (u16*)(ws);                         // 8 MB
  u16*   Wt   = (u16*)(ws + 8388608);               // 6 MB  (Wq^T | Wkv^T) [3072][1024]
  u16*   Wot  = (u16*)(ws + 14680064);              // 2 MB  Wo^T [1024][1024]
  float* bias = (float*)(ws + 16777216);            // 16 KB
  u16*   Cq   = (u16*)(ws + 16793600);              // 24 MB [4096][3072] (V third used)
  u16*   qb   = (u16*)(ws + 41959424);              // 8 MB [b,h,n,d]
  u16*   kb   = (u16*)(ws + 41959424 + 8388608);    // 8 MB
  u16*   vT   = (u16*)(ws + 41959424 + 2*8388608);  // 8 MB [b*h][d][n]
  u16*   ao   = (u16*)(ws + 41959424 + 3*8388608);  // 8 MB [4096][1024]

  k_pre<<<8208, 256, 0, stream>>>(x, g_ln, Wq, Wkv, Wo, mask, xn, Wt, Wot, bias);
  k_gemm_bt<4, true, true><<<dim3(32, 24), 256, 0, stream>>>(
      xn, Wt, Cq, g_q, g_k, qb, kb, ROWS_, E3_, DIM_);
  k_vt<<<dim3(32, 32), dim3(64, 4), 0, stream>>>(Cq, vT);
  k_attn<<<512, 256, 0, stream>>>(qb, kb, vT, bias, ao);
  k_gemm_bt<2, false, false><<<dim3(32, 16), 256, 0, stream>>>(
      ao, Wot, out, nullptr, nullptr, nullptr, nullptr, ROWS_, DIM_, DIM_);
}